// Round 10
// baseline (185.540 us; speedup 1.0000x reference)
//
#include <hip/hip_runtime.h>
#include <hip/hip_bf16.h>

// ---------------------------------------------------------------------------
// SelfAttention2d, fully-MFMA pipeline, fragment-major memory layouts.
// MFMA 16x16x32 bf16: A[m=il][k=q*8+j], B[col=il][k=q*8+j], C[row=q*4+r][col=il]
//
// Attention computes S TRANSPOSED (A=K, B=Q): pw lookups are ny-invariant
// registers, ph one read/ny, P needs only an 8B LDS write + b128 read.
//
// conv: 64pos x 32co tiles, 4-wave blocks in 2x2 (pos x co) arrangement so
// waves share A loads (same pos-tile) and B loads (same co-tile) via L1.
//
// Layouts:
//   XC   [b][kc 0..7][y 0..33][x 0..33][ci 32]  zero-padded image, bf16
//   WB2  [t9][coG6][nt4][kc8][lane64][8]        w_out frag-major
//   WK2  [coG6][nt4][kc8][lane64][8]            w_kqv frag-major
//   WA2  [coG2][nt4][kc4][lane64][8]            w_attn frag-major
//   VT   [bh][ny32][d16][ci 32]                 V^T frag-major
//   artX [b][kc4][pp1024][ci32]                 attn out, frag-major
//
// ws (ushort units, 7,262,208 B <= proven-safe 8,192,000):
//   WB2 0 / WK2 884736 / WA2 983040 / KRWB 999424 / KRHB 1000448 /
//   XC 1001472 (2,367,488) / ART2 3368960 (b=6,7 slots)
// d_out scratch (ushort): KS 0 / QS 1048576 / VT 2097152 / ART1 7340032 (b0..5)
// Order: prep -> xt(incl. halo zero) -> kqv -> attn -> attn_out -> conv
// ---------------------------------------------------------------------------

typedef short v8s __attribute__((ext_vector_type(8)));
typedef float v4f __attribute__((ext_vector_type(4)));

#define WB2_US   0u
#define WK2_US   884736u
#define WA2_US   983040u
#define KRWB_US  999424u
#define KRHB_US  1000448u
#define XC_US    1001472u
#define ART2_US  3368960u

#define KS_US    0u
#define QS_US    1048576u
#define VTS_US   2097152u
#define ART1_US  7340032u

#define QSCALE 0.360673760f   // 0.25 * log2(e)
#define SHIFT2 17.3123405f    // 12 * log2(e)

__device__ __forceinline__ unsigned short f2bs(float f) {
  __hip_bfloat16 h = __float2bfloat16(f);
  return *reinterpret_cast<unsigned short*>(&h);
}

// ---------------------------------------------------------------------------
__global__ __launch_bounds__(256) void prep_kernel(
    const float* __restrict__ w_out, const float* __restrict__ w_kqv,
    const float* __restrict__ w_attn, const float* __restrict__ krw,
    const float* __restrict__ krh, unsigned short* __restrict__ ws) {
  int i = blockIdx.x * 256 + threadIdx.x;
  if (i < 884736) {              // WB2[t][coG][nt][kc][lane][8]
    int j = i & 7, l = (i >> 3) & 63, kc = (i >> 9) & 7, nt = (i >> 12) & 3;
    int r = i >> 14; int coG = r % 6, t = r / 6;
    int co = coG * 64 + nt * 16 + (l & 15);
    int ci = kc * 32 + (l >> 4) * 8 + j;
    ws[WB2_US + i] = f2bs(w_out[(size_t)co * 2304 + ci * 9 + t]);
  } else if (i < 983040) {       // WK2[coG][nt][kc][lane][8]
    int o = i - 884736;
    int j = o & 7, l = (o >> 3) & 63, kc = (o >> 9) & 7, nt = (o >> 12) & 3;
    int coG = o >> 14;
    int co = coG * 64 + nt * 16 + (l & 15);
    int ci = kc * 32 + (l >> 4) * 8 + j;
    ws[WK2_US + o] = f2bs(w_kqv[co * 256 + ci]);
  } else if (i < 999424) {       // WA2[coG][nt][kc][lane][8]
    int o = i - 983040;
    int j = o & 7, l = (o >> 3) & 63, kc = (o >> 9) & 3, nt = (o >> 11) & 3;
    int coG = o >> 13;
    int co = coG * 64 + nt * 16 + (l & 15);
    int ci = kc * 32 + (l >> 4) * 8 + j;
    ws[WA2_US + o] = f2bs(w_attn[co * 128 + ci]);
  } else if (i < 1000448) {      // krw bf16 [64][16], row 63 zero
    int j = i - 999424; int c = j >> 4, d = j & 15;
    ws[KRWB_US + j] = (c < 63) ? f2bs(krw[c * 16 + d]) : (unsigned short)0;
  } else if (i < 1001472) {
    int j = i - 1000448; int c = j >> 4, d = j & 15;
    ws[KRHB_US + j] = (c < 63) ? f2bs(krh[c * 16 + d]) : (unsigned short)0;
  }
}

// ---------------------------------------------------------------------------
// x [b][ci][pos] fp32 -> XC[b][ci>>5][y+1][x+1][ci&31] bf16 via LDS tile.
// Blocks with blockIdx.x==0 additionally zero the halo of their 2 planes
// (border cells are disjoint from all interior writes).
__global__ __launch_bounds__(256) void xt_kernel(
    const float* __restrict__ x, unsigned short* __restrict__ xc) {
  __shared__ float t[64][65];
  int tid = threadIdx.x; int pl = tid & 63, cg = tid >> 6;
  int pos0 = blockIdx.x * 64, ci0 = blockIdx.y * 64, b = blockIdx.z;

  if (blockIdx.x == 0) {
    // 2 planes (kc = ci0/32, +1) x 528 border uint4 each
    for (int j = tid; j < 1056; j += 256) {
      int plane = j / 528;
      int u = j % 528;
      int p = u >> 2, cio = (u & 3) * 8;
      int y, xx2;
      if (p < 34)      { y = 0;           xx2 = p; }
      else if (p < 68) { y = 33;          xx2 = p - 34; }
      else if (p < 100){ y = p - 68 + 1;  xx2 = 0; }
      else             { y = p - 100 + 1; xx2 = 33; }
      int kc = (ci0 >> 5) + plane;
      uint4 z = {0u, 0u, 0u, 0u};
      *(uint4*)(xc + ((size_t)((b * 8 + kc) * 34 + y) * 34 + xx2) * 32 + cio) = z;
    }
  }

  const float* xb = x + ((size_t)(b * 256 + ci0)) * 1024 + pos0;
#pragma unroll
  for (int i = 0; i < 16; ++i) {
    int ci_l = cg * 16 + i;
    t[ci_l][pl] = xb[(size_t)ci_l * 1024 + pl];
  }
  __syncthreads();
#pragma unroll
  for (int i = 0; i < 16; ++i) {
    int pos_l = cg * 16 + i;
    int pos = pos0 + pos_l;
    int y = (pos >> 5) + 1, xx = (pos & 31) + 1;
    int ci = ci0 + pl;
    xc[((size_t)((b * 8 + (ci >> 5)) * 34 + y) * 34 + xx) * 32 + (ci & 31)] =
        f2bs(t[pl][pos_l]);
  }
}

// ---------------------------------------------------------------------------
// kqv GEMM: A-frags from XC (tap 1,1; contiguous 1KB loads), B from WK2.
__global__ __launch_bounds__(64) void kqv_mfma(
    const unsigned short* __restrict__ xc, const unsigned short* __restrict__ wk2,
    const float* __restrict__ bkqv, unsigned short* __restrict__ dq) {
  int lane = threadIdx.x; int il = lane & 15, q = lane >> 4;
  int m0 = blockIdx.x * 64, coG = blockIdx.y;
  int b = m0 >> 10, pos0 = m0 & 1023;
  int row0 = pos0 >> 5;
  v4f acc[4][4];
#pragma unroll
  for (int mt = 0; mt < 4; ++mt)
#pragma unroll
    for (int nt = 0; nt < 4; ++nt) acc[mt][nt] = (v4f){0.f, 0.f, 0.f, 0.f};

  int pix[4];
#pragma unroll
  for (int mt = 0; mt < 4; ++mt)
    pix[mt] = (row0 + (mt >> 1) + 1) * 34 + ((mt & 1) * 16 + il + 1);
  const unsigned short* bt = wk2 + (size_t)coG * 16384 + lane * 8;

#pragma unroll 2
  for (int kc = 0; kc < 8; ++kc) {
    v8s af[4], bf[4];
#pragma unroll
    for (int nt = 0; nt < 4; ++nt)
      bf[nt] = *(const v8s*)(bt + (nt * 8 + kc) * 512);
#pragma unroll
    for (int mt = 0; mt < 4; ++mt)
      af[mt] = *(const v8s*)(xc + ((size_t)(b * 8 + kc) * 1156 + pix[mt]) * 32 + q * 8);
#pragma unroll
    for (int mt = 0; mt < 4; ++mt)
#pragma unroll
      for (int nt = 0; nt < 4; ++nt)
        acc[mt][nt] = __builtin_amdgcn_mfma_f32_16x16x32_bf16(
            af[mt], bf[nt], acc[mt][nt], 0, 0, 0);
  }
  int co0 = coG * 64;
#pragma unroll
  for (int nt = 0; nt < 4; ++nt) {
    int cob = co0 + nt * 16;
    int co = cob + il;
    float bias = bkqv[co];
    int cls = cob >> 7;                  // 0:k 1:q 2:v (uniform per nt)
    int h = (cob >> 4) & 7;
    size_t bh = (size_t)(b * 8 + h);
#pragma unroll
    for (int mt = 0; mt < 4; ++mt) {
      int pos = pos0 + mt * 16 + q * 4;
      v4f a = acc[mt][nt];
#pragma unroll
      for (int r = 0; r < 4; ++r) {
        float v = a[r] + bias;
        int p = pos + r;
        if (cls == 0)      dq[KS_US + bh * 16384 + p * 16 + il] = f2bs(v);
        else if (cls == 1) dq[QS_US + bh * 16384 + p * 16 + il] = f2bs(v * QSCALE);
        else               dq[VTS_US + bh * 16384 + ((p >> 5) * 16 + il) * 32 + (p & 31)] = f2bs(v);
      }
    }
  }
}

// ---------------------------------------------------------------------------
// MFMA attention, S-transposed formulation. Block 256 = 4 waves; wave owns a
// 16-row m-tile. Lane (q,il) reg r holds S[m0+il][nb+q*4+r].
__global__ __launch_bounds__(256) void attn_mfma(
    unsigned short* __restrict__ dq, const unsigned short* __restrict__ krwb,
    const unsigned short* __restrict__ krhb, unsigned short* __restrict__ wsart) {
  __shared__ float lds[4][2448];
  int tid = threadIdx.x; int w = tid >> 6, lane = tid & 63;
  int il = lane & 15, q = lane >> 4;
  int bh = blockIdx.y; int b = bh >> 3, h = bh & 7;
  int m0 = blockIdx.x * 64 + w * 16;
  int my = m0 >> 5, mxb = m0 & 31;
  float* pw = lds[w];                       // [16 rows][stride 64]
  float* ph = pw + 1024;                    // [16 rows][stride 68], - SHIFT2
  unsigned short* pl = (unsigned short*)(ph + 1088);  // [16 rows][stride 40] bf16

  const v8s z8 = {0, 0, 0, 0, 0, 0, 0, 0};
  const v4f z4 = {0.f, 0.f, 0.f, 0.f};

  // Q frag: A-layout for table build == B-layout for S^T (same registers).
  const unsigned short* qrow = dq + QS_US + (size_t)bh * 16384 + (m0 + il) * 16;
  v8s qa = *(const v8s*)(qrow + (q & 1) * 8);
  qa = (q < 2) ? qa : z8;

  // PW / PH tables via MFMA (C row = m-row in tile, col = table col)
#pragma unroll
  for (int nt = 0; nt < 4; ++nt) {
    int c = nt * 16 + il;
    v8s bw = *(const v8s*)(krwb + c * 16 + (q & 1) * 8);
    v8s bhh = *(const v8s*)(krhb + c * 16 + (q & 1) * 8);
    bw = (q < 2) ? bw : z8;
    bhh = (q < 2) ? bhh : z8;
    v4f pwc = __builtin_amdgcn_mfma_f32_16x16x32_bf16(qa, bw, z4, 0, 0, 0);
    v4f phc = __builtin_amdgcn_mfma_f32_16x16x32_bf16(qa, bhh, z4, 0, 0, 0);
#pragma unroll
    for (int r = 0; r < 4; ++r) {
      pw[(q * 4 + r) * 64 + c] = pwc[r];
      ph[(q * 4 + r) * 68 + c] = phc[r] - SHIFT2;
    }
  }
  __builtin_amdgcn_wave_barrier();

  // pw lookups are ny-invariant per lane in the transposed scheme: hoist.
  float pwv[2][4];
#pragma unroll
  for (int nt2 = 0; nt2 < 2; ++nt2)
#pragma unroll
    for (int r = 0; r < 4; ++r)
      pwv[nt2][r] = pw[il * 64 + (nt2 * 16 + q * 4 + r) - mxb - il + 31];

  v4f oacc = z4;
  float sacc = 0.f;
  const unsigned short* kbase = dq + KS_US + (size_t)bh * 16384;
  const unsigned short* vbase = dq + VTS_US + (size_t)bh * 16384;

  for (int ny = 0; ny < 32; ++ny) {
    float phv = ph[il * 68 + (ny - my + 31)];
    v4f s[2];
#pragma unroll
    for (int nt2 = 0; nt2 < 2; ++nt2) {
      v8s kb = *(const v8s*)(kbase + (ny * 32 + nt2 * 16 + il) * 16 + (q & 1) * 8);
      kb = (q < 2) ? kb : z8;
      s[nt2] = __builtin_amdgcn_mfma_f32_16x16x32_bf16(kb, qa, z4, 0, 0, 0);
    }
#pragma unroll
    for (int nt2 = 0; nt2 < 2; ++nt2) {
      float p[4];
#pragma unroll
      for (int r = 0; r < 4; ++r) {
        float t = s[nt2][r] + pwv[nt2][r] + phv;
        p[r] = exp2f(t);
        sacc += p[r];
      }
      uint2 pk;
      pk.x = (unsigned)f2bs(p[0]) | ((unsigned)f2bs(p[1]) << 16);
      pk.y = (unsigned)f2bs(p[2]) | ((unsigned)f2bs(p[3]) << 16);
      *(uint2*)(pl + il * 40 + nt2 * 16 + q * 4) = pk;
    }
    __builtin_amdgcn_wave_barrier();
    v8s pf = *(const v8s*)(pl + il * 40 + q * 8);
    v8s vb = *(const v8s*)(vbase + (ny * 16 + il) * 32 + q * 8);
    oacc = __builtin_amdgcn_mfma_f32_16x16x32_bf16(pf, vb, oacc, 0, 0, 0);
    __builtin_amdgcn_wave_barrier();
  }

  // row sums: lane holds partial for row il; combine quads, then fetch per-r.
  sacc += __shfl_xor(sacc, 16);
  sacc += __shfl_xor(sacc, 32);

  unsigned short* abase = (b < 6) ? (dq + ART1_US + (size_t)b * 131072)
                                  : (wsart + (size_t)(b - 6) * 131072);
#pragma unroll
  for (int r = 0; r < 4; ++r) {
    float sr = __shfl(sacc, q * 4 + r);       // full sum for row q*4+r
    int m = m0 + q * 4 + r;
    int c = h * 16 + (m >> 6);                // ci of art
    int pp = (m & 63) * 16 + il;              // pos' of art
    abase[((c >> 5) * 1024 + pp) * 32 + (c & 31)] = f2bs(oacc[r] / sr);
  }
}

// ---------------------------------------------------------------------------
// attn_out GEMM: A from artX (contiguous), B from WA2 (frag-major).
__global__ __launch_bounds__(64) void attn_out_mfma(
    const unsigned short* __restrict__ dq, const unsigned short* __restrict__ wsart,
    const unsigned short* __restrict__ wa2, const float* __restrict__ ba,
    float* __restrict__ out) {
  int lane = threadIdx.x; int il = lane & 15, q = lane >> 4;
  int m0 = blockIdx.x * 64, coG = blockIdx.y;
  int b = m0 >> 10, pp0 = m0 & 1023;
  const unsigned short* ab = (b < 6) ? (dq + ART1_US + (size_t)b * 131072)
                                     : (wsart + (size_t)(b - 6) * 131072);
  const unsigned short* bt = wa2 + (size_t)coG * 8192 + lane * 8;
  v4f acc[4][4];
#pragma unroll
  for (int mt = 0; mt < 4; ++mt)
#pragma unroll
    for (int nt = 0; nt < 4; ++nt) acc[mt][nt] = (v4f){0.f, 0.f, 0.f, 0.f};
#pragma unroll
  for (int kc = 0; kc < 4; ++kc) {
    v8s af[4], bf[4];
#pragma unroll
    for (int nt = 0; nt < 4; ++nt)
      bf[nt] = *(const v8s*)(bt + (nt * 4 + kc) * 512);
#pragma unroll
    for (int mt = 0; mt < 4; ++mt)
      af[mt] = *(const v8s*)(ab + (kc * 1024 + pp0 + mt * 16 + il) * 32 + q * 8);
#pragma unroll
    for (int mt = 0; mt < 4; ++mt)
#pragma unroll
      for (int nt = 0; nt < 4; ++nt)
        acc[mt][nt] = __builtin_amdgcn_mfma_f32_16x16x32_bf16(
            af[mt], bf[nt], acc[mt][nt], 0, 0, 0);
  }
  int co0 = coG * 64;
#pragma unroll
  for (int nt = 0; nt < 4; ++nt) {
    int co = co0 + nt * 16 + il;
    float bias = ba[co];
#pragma unroll
    for (int mt = 0; mt < 4; ++mt) {
      v4f a = acc[mt][nt];
      float4 v; v.x = a[0] + bias; v.y = a[1] + bias;
      v.z = a[2] + bias; v.w = a[3] + bias;
      *(float4*)(out + ((size_t)(b * 512 + 384 + co)) * 1024 + pp0 + mt * 16 + q * 4) = v;
    }
  }
}

// ---------------------------------------------------------------------------
// conv3x3 via MFMA on XC. 4-wave blocks, 2x2 (pos x co) tile arrangement:
// waves 0,1 share co-tile (same B loads -> L1), waves 0,2 share pos-tile
// (same A loads -> L1). 64pos x 32co per wave; grid (8,6,8) = 1536 waves.
__global__ __launch_bounds__(256) void conv_mfma(
    const unsigned short* __restrict__ xc, const unsigned short* __restrict__ wb2,
    const float* __restrict__ bo, float* __restrict__ out) {
  int tid = threadIdx.x;
  int w = tid >> 6, lane = tid & 63;
  int il = lane & 15, q = lane >> 4;
  int pt = blockIdx.x * 2 + (w & 1);        // 16 pos-tiles of 64
  int cg = blockIdx.y * 2 + (w >> 1);       // 12 co-tiles of 32
  int b = blockIdx.z;
  int pos0 = pt * 64;
  int row0 = pos0 >> 5;
  int coG = cg >> 1, ntb = (cg & 1) * 2;    // into WB2 [coG6][nt4]
  v4f acc[4][2];
#pragma unroll
  for (int mt = 0; mt < 4; ++mt)
#pragma unroll
    for (int nt = 0; nt < 2; ++nt) acc[mt][nt] = (v4f){0.f, 0.f, 0.f, 0.f};

#pragma unroll
  for (int ky = 0; ky < 3; ++ky) {
#pragma unroll
    for (int kx = 0; kx < 3; ++kx) {
      const unsigned short* bt =
          wb2 + (size_t)((ky * 3 + kx) * 6 + coG) * 16384 + lane * 8;
      int pix[4];
#pragma unroll
      for (int mt = 0; mt < 4; ++mt)
        pix[mt] = (row0 + (mt >> 1) + ky) * 34 + ((mt & 1) * 16 + il + kx);
#pragma unroll 4
      for (int kc = 0; kc < 8; ++kc) {
        v8s bf[2], af[4];
#pragma unroll
        for (int nt = 0; nt < 2; ++nt)
          bf[nt] = *(const v8s*)(bt + ((ntb + nt) * 8 + kc) * 512);
#pragma unroll
        for (int mt = 0; mt < 4; ++mt)
          af[mt] = *(const v8s*)(xc + ((size_t)(b * 8 + kc) * 1156 + pix[mt]) * 32 + q * 8);
#pragma unroll
        for (int mt = 0; mt < 4; ++mt)
#pragma unroll
          for (int nt = 0; nt < 2; ++nt)
            acc[mt][nt] = __builtin_amdgcn_mfma_f32_16x16x32_bf16(
                af[mt], bf[nt], acc[mt][nt], 0, 0, 0);
      }
    }
  }
#pragma unroll
  for (int nt = 0; nt < 2; ++nt) {
    int co = cg * 32 + nt * 16 + il;
    float bias = bo[co];
#pragma unroll
    for (int mt = 0; mt < 4; ++mt) {
      v4f a = acc[mt][nt];
      float4 v; v.x = a[0] + bias; v.y = a[1] + bias;
      v.z = a[2] + bias; v.w = a[3] + bias;
      *(float4*)(out + ((size_t)(b * 512 + co)) * 1024 + pos0 + mt * 16 + q * 4) = v;
    }
  }
}

// ---------------------------------------------------------------------------
extern "C" void kernel_launch(void* const* d_in, const int* in_sizes, int n_in,
                              void* d_out, int out_size, void* d_ws, size_t ws_size,
                              hipStream_t stream) {
  const float* x      = (const float*)d_in[0];
  const float* b_out  = (const float*)d_in[2];
  const float* b_kqv  = (const float*)d_in[4];
  const float* b_attn = (const float*)d_in[6];
  const float* krw    = (const float*)d_in[7];
  const float* krh    = (const float*)d_in[8];
  unsigned short* ws = (unsigned short*)d_ws;
  float* out = (float*)d_out;
  unsigned short* dq = (unsigned short*)d_out;

  prep_kernel<<<3912, 256, 0, stream>>>(
      (const float*)d_in[1], (const float*)d_in[3], (const float*)d_in[5],
      krw, krh, ws);
  xt_kernel<<<dim3(16, 4, 8), 256, 0, stream>>>(x, ws + XC_US);
  kqv_mfma<<<dim3(128, 6), 64, 0, stream>>>(
      ws + XC_US, ws + WK2_US, b_kqv, dq);
  attn_mfma<<<dim3(16, 64), 256, 0, stream>>>(
      dq, ws + KRWB_US, ws + KRHB_US, ws + ART2_US);
  attn_out_mfma<<<dim3(128, 2), 64, 0, stream>>>(
      dq, ws + ART2_US, ws + WA2_US, b_attn, out);
  conv_mfma<<<dim3(8, 6, 8), 256, 0, stream>>>(
      ws + XC_US, ws + WB2_US, b_out, out);
}

// Round 12
// 183.878 us; speedup vs baseline: 1.0090x; 1.0090x over previous
//
#include <hip/hip_runtime.h>
#include <hip/hip_bf16.h>

// ---------------------------------------------------------------------------
// SelfAttention2d, fully-MFMA pipeline, fragment-major memory layouts.
// MFMA 16x16x32 bf16: A[m=il][k=q*8+j], B[col=il][k=q*8+j], C[row=q*4+r][col=il]
//
// Attention computes S TRANSPOSED (A=K, B=Q): pw lookups are ny-invariant
// registers, ph one read/ny, P needs only an 8B LDS write + b128 read.
//
// conv: 64pos x 64co per wave, single-wave blocks; loop order kc OUTER,
// 9 taps INNER so all taps of one kc hit the same 8.7 KB A-slab in L1.
// (Round-11 version had a 6x-too-large tap stride into WB2 -- fixed: the
//  t-stride is 98304 us, expressed as ((ky*3+kx)*6 + coG)*16384.)
//
// Layouts:
//   XC   [b][kc 0..7][y 0..33][x 0..33][ci 32]  zero-padded image, bf16
//   WB2  [t9][coG6][nt4][kc8][lane64][8]        w_out frag-major
//   WK2  [coG6][nt4][kc8][lane64][8]            w_kqv frag-major
//   WA2  [coG2][nt4][kc4][lane64][8]            w_attn frag-major
//   VT   [bh][ny32][d16][ci 32]                 V^T frag-major
//   artX [b][kc4][pp1024][ci32]                 attn out, frag-major
//
// ws (ushort units, 7,262,208 B <= proven-safe 8,192,000):
//   WB2 0 / WK2 884736 / WA2 983040 / KRWB 999424 / KRHB 1000448 /
//   XC 1001472 (2,367,488) / ART2 3368960 (b=6,7 slots)
// d_out scratch (ushort): KS 0 / QS 1048576 / VT 2097152 / ART1 7340032 (b0..5)
// Order: prep -> xt(incl. halo zero) -> kqv -> attn -> attn_out -> conv
// ---------------------------------------------------------------------------

typedef short v8s __attribute__((ext_vector_type(8)));
typedef float v4f __attribute__((ext_vector_type(4)));

#define WB2_US   0u
#define WK2_US   884736u
#define WA2_US   983040u
#define KRWB_US  999424u
#define KRHB_US  1000448u
#define XC_US    1001472u
#define ART2_US  3368960u

#define KS_US    0u
#define QS_US    1048576u
#define VTS_US   2097152u
#define ART1_US  7340032u

#define QSCALE 0.360673760f   // 0.25 * log2(e)
#define SHIFT2 17.3123405f    // 12 * log2(e)

__device__ __forceinline__ unsigned short f2bs(float f) {
  __hip_bfloat16 h = __float2bfloat16(f);
  return *reinterpret_cast<unsigned short*>(&h);
}

// ---------------------------------------------------------------------------
__global__ __launch_bounds__(256) void prep_kernel(
    const float* __restrict__ w_out, const float* __restrict__ w_kqv,
    const float* __restrict__ w_attn, const float* __restrict__ krw,
    const float* __restrict__ krh, unsigned short* __restrict__ ws) {
  int i = blockIdx.x * 256 + threadIdx.x;
  if (i < 884736) {              // WB2[t][coG][nt][kc][lane][8]
    int j = i & 7, l = (i >> 3) & 63, kc = (i >> 9) & 7, nt = (i >> 12) & 3;
    int r = i >> 14; int coG = r % 6, t = r / 6;
    int co = coG * 64 + nt * 16 + (l & 15);
    int ci = kc * 32 + (l >> 4) * 8 + j;
    ws[WB2_US + i] = f2bs(w_out[(size_t)co * 2304 + ci * 9 + t]);
  } else if (i < 983040) {       // WK2[coG][nt][kc][lane][8]
    int o = i - 884736;
    int j = o & 7, l = (o >> 3) & 63, kc = (o >> 9) & 7, nt = (o >> 12) & 3;
    int coG = o >> 14;
    int co = coG * 64 + nt * 16 + (l & 15);
    int ci = kc * 32 + (l >> 4) * 8 + j;
    ws[WK2_US + o] = f2bs(w_kqv[co * 256 + ci]);
  } else if (i < 999424) {       // WA2[coG][nt][kc][lane][8]
    int o = i - 983040;
    int j = o & 7, l = (o >> 3) & 63, kc = (o >> 9) & 3, nt = (o >> 11) & 3;
    int coG = o >> 13;
    int co = coG * 64 + nt * 16 + (l & 15);
    int ci = kc * 32 + (l >> 4) * 8 + j;
    ws[WA2_US + o] = f2bs(w_attn[co * 128 + ci]);
  } else if (i < 1000448) {      // krw bf16 [64][16], row 63 zero
    int j = i - 999424; int c = j >> 4, d = j & 15;
    ws[KRWB_US + j] = (c < 63) ? f2bs(krw[c * 16 + d]) : (unsigned short)0;
  } else if (i < 1001472) {
    int j = i - 1000448; int c = j >> 4, d = j & 15;
    ws[KRHB_US + j] = (c < 63) ? f2bs(krh[c * 16 + d]) : (unsigned short)0;
  }
}

// ---------------------------------------------------------------------------
// x [b][ci][pos] fp32 -> XC[b][ci>>5][y+1][x+1][ci&31] bf16 via LDS tile.
// Blocks with blockIdx.x==0 additionally zero the halo of their 2 planes.
__global__ __launch_bounds__(256) void xt_kernel(
    const float* __restrict__ x, unsigned short* __restrict__ xc) {
  __shared__ float t[64][65];
  int tid = threadIdx.x; int pl = tid & 63, cg = tid >> 6;
  int pos0 = blockIdx.x * 64, ci0 = blockIdx.y * 64, b = blockIdx.z;

  if (blockIdx.x == 0) {
    for (int j = tid; j < 1056; j += 256) {
      int plane = j / 528;
      int u = j % 528;
      int p = u >> 2, cio = (u & 3) * 8;
      int y, xx2;
      if (p < 34)      { y = 0;           xx2 = p; }
      else if (p < 68) { y = 33;          xx2 = p - 34; }
      else if (p < 100){ y = p - 68 + 1;  xx2 = 0; }
      else             { y = p - 100 + 1; xx2 = 33; }
      int kc = (ci0 >> 5) + plane;
      uint4 z = {0u, 0u, 0u, 0u};
      *(uint4*)(xc + ((size_t)((b * 8 + kc) * 34 + y) * 34 + xx2) * 32 + cio) = z;
    }
  }

  const float* xb = x + ((size_t)(b * 256 + ci0)) * 1024 + pos0;
#pragma unroll
  for (int i = 0; i < 16; ++i) {
    int ci_l = cg * 16 + i;
    t[ci_l][pl] = xb[(size_t)ci_l * 1024 + pl];
  }
  __syncthreads();
#pragma unroll
  for (int i = 0; i < 16; ++i) {
    int pos_l = cg * 16 + i;
    int pos = pos0 + pos_l;
    int y = (pos >> 5) + 1, xx = (pos & 31) + 1;
    int ci = ci0 + pl;
    xc[((size_t)((b * 8 + (ci >> 5)) * 34 + y) * 34 + xx) * 32 + (ci & 31)] =
        f2bs(t[pl][pos_l]);
  }
}

// ---------------------------------------------------------------------------
// kqv GEMM: A-frags from XC (tap 1,1; contiguous 1KB loads), B from WK2.
__global__ __launch_bounds__(64) void kqv_mfma(
    const unsigned short* __restrict__ xc, const unsigned short* __restrict__ wk2,
    const float* __restrict__ bkqv, unsigned short* __restrict__ dq) {
  int lane = threadIdx.x; int il = lane & 15, q = lane >> 4;
  int m0 = blockIdx.x * 64, coG = blockIdx.y;
  int b = m0 >> 10, pos0 = m0 & 1023;
  int row0 = pos0 >> 5;
  v4f acc[4][4];
#pragma unroll
  for (int mt = 0; mt < 4; ++mt)
#pragma unroll
    for (int nt = 0; nt < 4; ++nt) acc[mt][nt] = (v4f){0.f, 0.f, 0.f, 0.f};

  int pix[4];
#pragma unroll
  for (int mt = 0; mt < 4; ++mt)
    pix[mt] = (row0 + (mt >> 1) + 1) * 34 + ((mt & 1) * 16 + il + 1);
  const unsigned short* bt = wk2 + (size_t)coG * 16384 + lane * 8;

#pragma unroll 2
  for (int kc = 0; kc < 8; ++kc) {
    v8s af[4], bf[4];
#pragma unroll
    for (int nt = 0; nt < 4; ++nt)
      bf[nt] = *(const v8s*)(bt + (nt * 8 + kc) * 512);
#pragma unroll
    for (int mt = 0; mt < 4; ++mt)
      af[mt] = *(const v8s*)(xc + ((size_t)(b * 8 + kc) * 1156 + pix[mt]) * 32 + q * 8);
#pragma unroll
    for (int mt = 0; mt < 4; ++mt)
#pragma unroll
      for (int nt = 0; nt < 4; ++nt)
        acc[mt][nt] = __builtin_amdgcn_mfma_f32_16x16x32_bf16(
            af[mt], bf[nt], acc[mt][nt], 0, 0, 0);
  }
  int co0 = coG * 64;
#pragma unroll
  for (int nt = 0; nt < 4; ++nt) {
    int cob = co0 + nt * 16;
    int co = cob + il;
    float bias = bkqv[co];
    int cls = cob >> 7;                  // 0:k 1:q 2:v (uniform per nt)
    int h = (cob >> 4) & 7;
    size_t bh = (size_t)(b * 8 + h);
#pragma unroll
    for (int mt = 0; mt < 4; ++mt) {
      int pos = pos0 + mt * 16 + q * 4;
      v4f a = acc[mt][nt];
#pragma unroll
      for (int r = 0; r < 4; ++r) {
        float v = a[r] + bias;
        int p = pos + r;
        if (cls == 0)      dq[KS_US + bh * 16384 + p * 16 + il] = f2bs(v);
        else if (cls == 1) dq[QS_US + bh * 16384 + p * 16 + il] = f2bs(v * QSCALE);
        else               dq[VTS_US + bh * 16384 + ((p >> 5) * 16 + il) * 32 + (p & 31)] = f2bs(v);
      }
    }
  }
}

// ---------------------------------------------------------------------------
// MFMA attention, S-transposed formulation. Block 256 = 4 waves; wave owns a
// 16-row m-tile. Lane (q,il) reg r holds S[m0+il][nb+q*4+r].
__global__ __launch_bounds__(256) void attn_mfma(
    unsigned short* __restrict__ dq, const unsigned short* __restrict__ krwb,
    const unsigned short* __restrict__ krhb, unsigned short* __restrict__ wsart) {
  __shared__ float lds[4][2448];
  int tid = threadIdx.x; int w = tid >> 6, lane = tid & 63;
  int il = lane & 15, q = lane >> 4;
  int bh = blockIdx.y; int b = bh >> 3, h = bh & 7;
  int m0 = blockIdx.x * 64 + w * 16;
  int my = m0 >> 5, mxb = m0 & 31;
  float* pw = lds[w];                       // [16 rows][stride 64]
  float* ph = pw + 1024;                    // [16 rows][stride 68], - SHIFT2
  unsigned short* pl = (unsigned short*)(ph + 1088);  // [16 rows][stride 40] bf16

  const v8s z8 = {0, 0, 0, 0, 0, 0, 0, 0};
  const v4f z4 = {0.f, 0.f, 0.f, 0.f};

  const unsigned short* qrow = dq + QS_US + (size_t)bh * 16384 + (m0 + il) * 16;
  v8s qa = *(const v8s*)(qrow + (q & 1) * 8);
  qa = (q < 2) ? qa : z8;

#pragma unroll
  for (int nt = 0; nt < 4; ++nt) {
    int c = nt * 16 + il;
    v8s bw = *(const v8s*)(krwb + c * 16 + (q & 1) * 8);
    v8s bhh = *(const v8s*)(krhb + c * 16 + (q & 1) * 8);
    bw = (q < 2) ? bw : z8;
    bhh = (q < 2) ? bhh : z8;
    v4f pwc = __builtin_amdgcn_mfma_f32_16x16x32_bf16(qa, bw, z4, 0, 0, 0);
    v4f phc = __builtin_amdgcn_mfma_f32_16x16x32_bf16(qa, bhh, z4, 0, 0, 0);
#pragma unroll
    for (int r = 0; r < 4; ++r) {
      pw[(q * 4 + r) * 64 + c] = pwc[r];
      ph[(q * 4 + r) * 68 + c] = phc[r] - SHIFT2;
    }
  }
  __builtin_amdgcn_wave_barrier();

  float pwv[2][4];
#pragma unroll
  for (int nt2 = 0; nt2 < 2; ++nt2)
#pragma unroll
    for (int r = 0; r < 4; ++r)
      pwv[nt2][r] = pw[il * 64 + (nt2 * 16 + q * 4 + r) - mxb - il + 31];

  v4f oacc = z4;
  float sacc = 0.f;
  const unsigned short* kbase = dq + KS_US + (size_t)bh * 16384;
  const unsigned short* vbase = dq + VTS_US + (size_t)bh * 16384;

  for (int ny = 0; ny < 32; ++ny) {
    float phv = ph[il * 68 + (ny - my + 31)];
    v4f s[2];
#pragma unroll
    for (int nt2 = 0; nt2 < 2; ++nt2) {
      v8s kb = *(const v8s*)(kbase + (ny * 32 + nt2 * 16 + il) * 16 + (q & 1) * 8);
      kb = (q < 2) ? kb : z8;
      s[nt2] = __builtin_amdgcn_mfma_f32_16x16x32_bf16(kb, qa, z4, 0, 0, 0);
    }
#pragma unroll
    for (int nt2 = 0; nt2 < 2; ++nt2) {
      float p[4];
#pragma unroll
      for (int r = 0; r < 4; ++r) {
        float t = s[nt2][r] + pwv[nt2][r] + phv;
        p[r] = exp2f(t);
        sacc += p[r];
      }
      uint2 pk;
      pk.x = (unsigned)f2bs(p[0]) | ((unsigned)f2bs(p[1]) << 16);
      pk.y = (unsigned)f2bs(p[2]) | ((unsigned)f2bs(p[3]) << 16);
      *(uint2*)(pl + il * 40 + nt2 * 16 + q * 4) = pk;
    }
    __builtin_amdgcn_wave_barrier();
    v8s pf = *(const v8s*)(pl + il * 40 + q * 8);
    v8s vb = *(const v8s*)(vbase + (ny * 16 + il) * 32 + q * 8);
    oacc = __builtin_amdgcn_mfma_f32_16x16x32_bf16(pf, vb, oacc, 0, 0, 0);
    __builtin_amdgcn_wave_barrier();
  }

  sacc += __shfl_xor(sacc, 16);
  sacc += __shfl_xor(sacc, 32);

  unsigned short* abase = (b < 6) ? (dq + ART1_US + (size_t)b * 131072)
                                  : (wsart + (size_t)(b - 6) * 131072);
#pragma unroll
  for (int r = 0; r < 4; ++r) {
    float sr = __shfl(sacc, q * 4 + r);
    int m = m0 + q * 4 + r;
    int c = h * 16 + (m >> 6);
    int pp = (m & 63) * 16 + il;
    abase[((c >> 5) * 1024 + pp) * 32 + (c & 31)] = f2bs(oacc[r] / sr);
  }
}

// ---------------------------------------------------------------------------
// attn_out GEMM: A from artX (contiguous), B from WA2 (frag-major).
__global__ __launch_bounds__(64) void attn_out_mfma(
    const unsigned short* __restrict__ dq, const unsigned short* __restrict__ wsart,
    const unsigned short* __restrict__ wa2, const float* __restrict__ ba,
    float* __restrict__ out) {
  int lane = threadIdx.x; int il = lane & 15, q = lane >> 4;
  int m0 = blockIdx.x * 64, coG = blockIdx.y;
  int b = m0 >> 10, pp0 = m0 & 1023;
  const unsigned short* ab = (b < 6) ? (dq + ART1_US + (size_t)b * 131072)
                                     : (wsart + (size_t)(b - 6) * 131072);
  const unsigned short* bt = wa2 + (size_t)coG * 8192 + lane * 8;
  v4f acc[4][4];
#pragma unroll
  for (int mt = 0; mt < 4; ++mt)
#pragma unroll
    for (int nt = 0; nt < 4; ++nt) acc[mt][nt] = (v4f){0.f, 0.f, 0.f, 0.f};
#pragma unroll
  for (int kc = 0; kc < 4; ++kc) {
    v8s af[4], bf[4];
#pragma unroll
    for (int nt = 0; nt < 4; ++nt)
      bf[nt] = *(const v8s*)(bt + (nt * 4 + kc) * 512);
#pragma unroll
    for (int mt = 0; mt < 4; ++mt)
      af[mt] = *(const v8s*)(ab + (kc * 1024 + pp0 + mt * 16 + il) * 32 + q * 8);
#pragma unroll
    for (int mt = 0; mt < 4; ++mt)
#pragma unroll
      for (int nt = 0; nt < 4; ++nt)
        acc[mt][nt] = __builtin_amdgcn_mfma_f32_16x16x32_bf16(
            af[mt], bf[nt], acc[mt][nt], 0, 0, 0);
  }
  int co0 = coG * 64;
#pragma unroll
  for (int nt = 0; nt < 4; ++nt) {
    int co = co0 + nt * 16 + il;
    float bias = ba[co];
#pragma unroll
    for (int mt = 0; mt < 4; ++mt) {
      v4f a = acc[mt][nt];
      float4 v; v.x = a[0] + bias; v.y = a[1] + bias;
      v.z = a[2] + bias; v.w = a[3] + bias;
      *(float4*)(out + ((size_t)(b * 512 + 384 + co)) * 1024 + pp0 + mt * 16 + q * 4) = v;
    }
  }
}

// ---------------------------------------------------------------------------
// conv3x3 via MFMA on XC: 64pos x 64co per wave, single-wave blocks.
// kc OUTER, taps INNER: all 9 taps of a kc read one 8.7KB slab -> L1 hits.
// WB2 t-stride is 98304 us == ((ky*3+kx)*6 + coG)*16384 form (round-11 bug fixed).
__global__ __launch_bounds__(64) void conv_mfma(
    const unsigned short* __restrict__ xc, const unsigned short* __restrict__ wb2,
    const float* __restrict__ bo, float* __restrict__ out) {
  int lane = threadIdx.x; int il = lane & 15, q = lane >> 4;
  int pt = blockIdx.x, coG = blockIdx.y, b = blockIdx.z;
  int pos0 = pt * 64;
  int row0 = pos0 >> 5;
  v4f acc[4][4];
#pragma unroll
  for (int mt = 0; mt < 4; ++mt)
#pragma unroll
    for (int nt = 0; nt < 4; ++nt) acc[mt][nt] = (v4f){0.f, 0.f, 0.f, 0.f};

  int pix0[4];
#pragma unroll
  for (int mt = 0; mt < 4; ++mt)
    pix0[mt] = (row0 + (mt >> 1)) * 34 + ((mt & 1) * 16 + il);

  for (int kc = 0; kc < 8; ++kc) {
    const unsigned short* akc = xc + (size_t)(b * 8 + kc) * 36992 + q * 8;
    const unsigned short* bkc = wb2 + kc * 512 + lane * 8;
#pragma unroll
    for (int ky = 0; ky < 3; ++ky) {
#pragma unroll
      for (int kx = 0; kx < 3; ++kx) {
        const unsigned short* bt =
            bkc + (size_t)((ky * 3 + kx) * 6 + coG) * 16384;
        v8s bf[4], af[4];
#pragma unroll
        for (int nt = 0; nt < 4; ++nt)
          bf[nt] = *(const v8s*)(bt + nt * 4096);
#pragma unroll
        for (int mt = 0; mt < 4; ++mt)
          af[mt] = *(const v8s*)(akc + (size_t)(pix0[mt] + ky * 34 + kx) * 32);
#pragma unroll
        for (int mt = 0; mt < 4; ++mt)
#pragma unroll
          for (int nt = 0; nt < 4; ++nt)
            acc[mt][nt] = __builtin_amdgcn_mfma_f32_16x16x32_bf16(
                af[mt], bf[nt], acc[mt][nt], 0, 0, 0);
      }
    }
  }
  int co0 = coG * 64;
#pragma unroll
  for (int nt = 0; nt < 4; ++nt) {
    int co = co0 + nt * 16 + il;
    float bias = bo[co];
#pragma unroll
    for (int mt = 0; mt < 4; ++mt) {
      v4f a = acc[mt][nt];
      float4 v; v.x = a[0] + bias; v.y = a[1] + bias;
      v.z = a[2] + bias; v.w = a[3] + bias;
      *(float4*)(out + ((size_t)(b * 512 + co)) * 1024 + pos0 + mt * 16 + q * 4) = v;
    }
  }
}

// ---------------------------------------------------------------------------
extern "C" void kernel_launch(void* const* d_in, const int* in_sizes, int n_in,
                              void* d_out, int out_size, void* d_ws, size_t ws_size,
                              hipStream_t stream) {
  const float* x      = (const float*)d_in[0];
  const float* b_out  = (const float*)d_in[2];
  const float* b_kqv  = (const float*)d_in[4];
  const float* b_attn = (const float*)d_in[6];
  const float* krw    = (const float*)d_in[7];
  const float* krh    = (const float*)d_in[8];
  unsigned short* ws = (unsigned short*)d_ws;
  float* out = (float*)d_out;
  unsigned short* dq = (unsigned short*)d_out;

  prep_kernel<<<3912, 256, 0, stream>>>(
      (const float*)d_in[1], (const float*)d_in[3], (const float*)d_in[5],
      krw, krh, ws);
  xt_kernel<<<dim3(16, 4, 8), 256, 0, stream>>>(x, ws + XC_US);
  kqv_mfma<<<dim3(128, 6), 64, 0, stream>>>(
      ws + XC_US, ws + WK2_US, b_kqv, dq);
  attn_mfma<<<dim3(16, 64), 256, 0, stream>>>(
      dq, ws + KRWB_US, ws + KRHB_US, ws + ART2_US);
  attn_out_mfma<<<dim3(128, 2), 64, 0, stream>>>(
      dq, ws + ART2_US, ws + WA2_US, b_attn, out);
  conv_mfma<<<dim3(16, 6, 8), 64, 0, stream>>>(
      ws + XC_US, ws + WB2_US, b_out, out);
}